// Round 2
// baseline (3160.720 us; speedup 1.0000x reference)
//
#include <hip/hip_runtime.h>
#include <hip/hip_bf16.h>
#include <math.h>

typedef __hip_bfloat16 bf16;

#define BB  4
#define NN  4096
#define SS  1024
#define KNS 32
#define C1  70

__device__ __forceinline__ float b2f(bf16 x){ return __bfloat162float(x); }

__device__ __forceinline__ float ld(const void* p, size_t i, bool F){
    return F ? ((const float*)p)[i] : __bfloat162float(((const bf16*)p)[i]);
}
__device__ __forceinline__ void st(void* p, size_t i, float v, bool F){
    if (F) ((float*)p)[i] = v; else ((bf16*)p)[i] = __float2bfloat16(v);
}

// ---------------- init: dtype detect + zero stats ----------------
__global__ void init_kernel(const void* xyz, double* __restrict__ M,
                            double* __restrict__ sums, int* __restrict__ flag){
    __shared__ int cnt;
    const int t = threadIdx.x;
    if (t == 0) cnt = 0;
    if (t < 105) M[t] = 0.0;
    if (t < 256) sums[t] = 0.0;
    __syncthreads();
    int c = 0;
    for (int i = t; i < 2048; i += 256){
        float v = __bfloat162float(((const bf16*)xyz)[i]);
        if (!(fabsf(v) <= 1.5f)) c++;   // catches NaN too
    }
    atomicAdd(&cnt, c);
    __syncthreads();
    if (t == 0) *flag = (cnt > 10) ? 1 : 0;
}

// ---------------- FPS ----------------
__global__ __launch_bounds__(512) void fps_kernel(const void* __restrict__ xyz,
        float* __restrict__ nxf, void* __restrict__ out, const int* __restrict__ flag){
    __shared__ float sx[NN], sy[NN], sz[NN];
    __shared__ int   sidx[SS];
    __shared__ float rv[8];
    __shared__ int   ri[8];
    __shared__ int   scur;
    const bool F = (*flag != 0);
    const int b = blockIdx.x, t = threadIdx.x;
    for (int i = t; i < NN; i += 512){
        sx[i] = ld(xyz, (size_t)(b*NN+i)*3+0, F);
        sy[i] = ld(xyz, (size_t)(b*NN+i)*3+1, F);
        sz[i] = ld(xyz, (size_t)(b*NN+i)*3+2, F);
    }
    float mind[8];
#pragma unroll
    for (int j = 0; j < 8; j++) mind[j] = 1e10f;
    if (t == 0) sidx[0] = 0;
    __syncthreads();
    int cur = 0;
    const int base = t*8;
    for (int s = 1; s < SS; s++){
        const float px = sx[cur], py = sy[cur], pz = sz[cur];
        float bd = -1.0f; int bi = 0;
#pragma unroll
        for (int j = 0; j < 8; j++){
            float dx = __fsub_rn(sx[base+j], px);
            float dy = __fsub_rn(sy[base+j], py);
            float dz = __fsub_rn(sz[base+j], pz);
            float d  = __fadd_rn(__fadd_rn(__fmul_rn(dx,dx), __fmul_rn(dy,dy)), __fmul_rn(dz,dz));
            float m = fminf(mind[j], d); mind[j] = m;
            if (m > bd){ bd = m; bi = base + j; }
        }
#pragma unroll
        for (int off = 32; off > 0; off >>= 1){
            float od = __shfl_down(bd, off);
            int   oi = __shfl_down(bi, off);
            if (od > bd || (od == bd && oi < bi)){ bd = od; bi = oi; }
        }
        if ((t & 63) == 0){ rv[t>>6] = bd; ri[t>>6] = bi; }
        __syncthreads();
        if (t == 0){
            float v = rv[0]; int ix = ri[0];
#pragma unroll
            for (int k = 1; k < 8; k++){
                if (rv[k] > v || (rv[k] == v && ri[k] < ix)){ v = rv[k]; ix = ri[k]; }
            }
            scur = ix; sidx[s] = ix;
        }
        __syncthreads();
        cur = scur;
    }
    const size_t o1 = (size_t)BB*SS*128;
    for (int s = t; s < SS; s += 512){
        int i = sidx[s];
        float X = sx[i], Y = sy[i], Z = sz[i];
        nxf[(b*SS+s)*3+0] = X; nxf[(b*SS+s)*3+1] = Y; nxf[(b*SS+s)*3+2] = Z;
        st(out, o1 + (size_t)(b*SS+s)*3+0, X, F);
        st(out, o1 + (size_t)(b*SS+s)*3+1, Y, F);
        st(out, o1 + (size_t)(b*SS+s)*3+2, Z, F);
    }
}

// ---------------- ball query ----------------
__global__ __launch_bounds__(256) void ball_kernel(const void* __restrict__ xyz,
        const float* __restrict__ nxf, int* __restrict__ idx, const int* __restrict__ flag){
    __shared__ float sx[NN], sy[NN], sz[NN];
    const bool F = (*flag != 0);
    const int b = blockIdx.x, t = threadIdx.x;
    for (int i = t; i < NN; i += 256){
        sx[i] = ld(xyz, (size_t)(b*NN+i)*3+0, F);
        sy[i] = ld(xyz, (size_t)(b*NN+i)*3+1, F);
        sz[i] = ld(xyz, (size_t)(b*NN+i)*3+2, F);
    }
    __syncthreads();
    const int s = blockIdx.y*256 + t;
    const float px = nxf[(b*SS+s)*3+0];
    const float py = nxf[(b*SS+s)*3+1];
    const float pz = nxf[(b*SS+s)*3+2];
    const float R2 = 0.2f*0.2f;
    int* op = idx + (size_t)(b*SS+s)*KNS;
    int cnt = 0;
    for (int i = 0; i < NN; i++){
        float dx = __fsub_rn(px, sx[i]);
        float dy = __fsub_rn(py, sy[i]);
        float dz = __fsub_rn(pz, sz[i]);
        float d2 = __fadd_rn(__fadd_rn(__fmul_rn(dx,dx), __fmul_rn(dy,dy)), __fmul_rn(dz,dz));
        if (d2 < R2){
            op[cnt++] = i;
            if (cnt == KNS) break;
        }
    }
    for (; cnt < KNS; cnt++) op[cnt] = -1;
}

// ---------------- BN1 stats: 14x14 moment matrix of extended coc ----------------
__global__ __launch_bounds__(128) void bn1_stats(const void* __restrict__ xyz,
        const int* __restrict__ idx, const void* __restrict__ fpt, double* __restrict__ M,
        const int* __restrict__ flag){
    __shared__ float cs[128][14];
    const bool F = (*flag != 0);
    const int t = threadIdx.x;
    int ci = 0, cj = 0;
    if (t < 105){
        int e = t, i = 0, off = 0;
        while (e - off >= 14 - i){ off += 14 - i; i++; }
        ci = i; cj = i + (e - off);
    }
    float fx[8], fy[8], fz[8];
#pragma unroll
    for (int v = 0; v < 8; v++){
        fx[v] = ld(fpt, v*3+0, F); fy[v] = ld(fpt, v*3+1, F); fz[v] = ld(fpt, v*3+2, F);
    }
    double acc = 0.0;
    const int base = blockIdx.x * 1024;
    for (int st8 = 0; st8 < 8; st8++){
        int e = base + st8*128 + t;
        int row = e >> 3, v = e & 7;
        int b = row >> 15;
        int id = idx[row];
        float gx = 0.f, gy = 0.f, gz = 0.f;
        if (id >= 0){
            gx = ld(xyz, (size_t)(b*NN+id)*3+0, F);
            gy = ld(xyz, (size_t)(b*NN+id)*3+1, F);
            gz = ld(xyz, (size_t)(b*NN+id)*3+2, F);
        }
        float ax = gx - fx[v], ay = gy - fy[v], az = gz - fz[v];
        float eu = sqrtf(ax*ax + ay*ay + az*az);
        cs[t][0] = -ax; cs[t][1] = -ay; cs[t][2] = -az;
        cs[t][3] =  ax; cs[t][4] =  ay; cs[t][5] =  az;
        cs[t][6] = eu;  cs[t][7] = gx;  cs[t][8] = gy; cs[t][9] = gz;
        cs[t][10] = fx[v]; cs[t][11] = fy[v]; cs[t][12] = fz[v]; cs[t][13] = 1.0f;
        __syncthreads();
        if (t < 105){
            float p = 0.f;
            for (int u = 0; u < 128; u++) p = fmaf(cs[u][ci], cs[u][cj], p);
            acc += (double)p;
        }
        __syncthreads();
    }
    if (t < 105) atomicAdd(&M[t], acc);
}

// ---------------- BN1 finalize ----------------
__global__ __launch_bounds__(128) void bn1_final(const double* __restrict__ M,
        const void* __restrict__ w10, const void* __restrict__ b10,
        const void* __restrict__ g1, const void* __restrict__ bt1, float* __restrict__ bn1,
        const int* __restrict__ flag){
    __shared__ double Mm[14][14];
    __shared__ double mv[14];
    const bool F = (*flag != 0);
    const int t = threadIdx.x;
    if (t < 105){
        int e = t, i = 0, off = 0;
        while (e - off >= 14 - i){ off += 14 - i; i++; }
        int j = i + (e - off);
        double val = M[t];
        Mm[i][j] = val; Mm[j][i] = val;
    }
    __syncthreads();
    const double K = 1048576.0;
    if (t < 14) mv[t] = Mm[t][13] / K;
    __syncthreads();
    if (t < 64){
        double wc[13];
        for (int i = 0; i < 13; i++) wc[i] = (double)ld(w10, i*64+t, F);
        double mean = (double)ld(b10, t, F);
        for (int i = 0; i < 13; i++) mean += mv[i]*wc[i];
        double var = 0.0;
        for (int i = 0; i < 13; i++)
            for (int j = 0; j < 13; j++)
                var += wc[i]*wc[j]*(Mm[i][j]/K - mv[i]*mv[j]);
        float sc = ld(g1, t, F) / sqrtf((float)var + 1e-5f);
        bn1[t] = sc;
        bn1[64+t] = ld(bt1, t, F) - (float)mean * sc;
    }
}

// ---------------- m1 MLP + frame softmax attention ----------------
__global__ __launch_bounds__(256) void m1_kernel(
        const void* __restrict__ xyz, const void* __restrict__ f, const void* __restrict__ fpt,
        const void* __restrict__ w10, const void* __restrict__ b10,
        const void* __restrict__ w11, const void* __restrict__ b11,
        const float* __restrict__ nxf, const int* __restrict__ idx,
        const float* __restrict__ bn1, float* __restrict__ agg, const int* __restrict__ flag){
    __shared__ float W11s[64*C1];
    __shared__ float a1s[4][512];
    const bool F = (*flag != 0);
    const int t = threadIdx.x, lane = t & 63, w = t >> 6;
    for (int e = t; e < 64*C1; e += 256) W11s[e] = ld(w11, e, F);
    float W10c[13];
#pragma unroll
    for (int i = 0; i < 13; i++) W10c[i] = ld(w10, i*64+lane, F);
    const float b10v = ld(b10, lane, F);
    const float sc1 = bn1[lane], sh1 = bn1[64+lane];
    const float b11a = ld(b11, lane, F);
    const float b11b = (lane < 6) ? ld(b11, 64+lane, F) : 0.f;
    float fx[8], fy[8], fz[8];
#pragma unroll
    for (int v = 0; v < 8; v++){
        fx[v] = ld(fpt, v*3+0, F); fy[v] = ld(fpt, v*3+1, F); fz[v] = ld(fpt, v*3+2, F);
    }
    __syncthreads();
    for (int it = 0; it < 64; it++){
        const int row = blockIdx.x*256 + it*4 + w;
        const int b = row >> 15, s = (row >> 5) & 1023;
        const int id = idx[row];
        float gx = 0.f, gy = 0.f, gz = 0.f, fv0 = 0.f, fv1 = 0.f;
        if (id >= 0){
            gx = ld(xyz, (size_t)(b*NN+id)*3+0, F);
            gy = ld(xyz, (size_t)(b*NN+id)*3+1, F);
            gz = ld(xyz, (size_t)(b*NN+id)*3+2, F);
            if (lane >= 6) fv0 = ld(f, (size_t)(b*NN+id)*64 + (lane-6), F);
            if (lane < 6)  fv1 = ld(f, (size_t)(b*NN+id)*64 + (58+lane), F);
        }
        const float nxx = nxf[(b*SS+s)*3+0], nxy = nxf[(b*SS+s)*3+1], nxz = nxf[(b*SS+s)*3+2];
        float gf0;
        if (lane == 0) gf0 = gx; else if (lane == 1) gf0 = gy; else if (lane == 2) gf0 = gz;
        else if (lane == 3) gf0 = gx - nxx; else if (lane == 4) gf0 = gy - nxy;
        else if (lane == 5) gf0 = gz - nxz; else gf0 = fv0;
        const float gf1 = fv1;
        // phase A: z1 -> bn -> relu, lane = hidden channel
#pragma unroll
        for (int v = 0; v < 8; v++){
            float ax = gx - fx[v], ay = gy - fy[v], az = gz - fz[v];
            float eu = sqrtf(ax*ax + ay*ay + az*az);
            float z = b10v;
            z = fmaf(-ax, W10c[0], z); z = fmaf(-ay, W10c[1], z); z = fmaf(-az, W10c[2], z);
            z = fmaf( ax, W10c[3], z); z = fmaf( ay, W10c[4], z); z = fmaf( az, W10c[5], z);
            z = fmaf( eu, W10c[6], z);
            z = fmaf( gx, W10c[7], z); z = fmaf( gy, W10c[8], z); z = fmaf( gz, W10c[9], z);
            z = fmaf(fx[v], W10c[10], z); z = fmaf(fy[v], W10c[11], z); z = fmaf(fz[v], W10c[12], z);
            float a1 = fmaxf(fmaf(z, sc1, sh1), 0.f);
            a1s[w][lane*8+v] = a1;
        }
        __syncthreads();
        // phase B: a = a1 @ W11 + b11, lane = output channel (+64 for lanes<6)
        float acc0[8], acc1[8];
#pragma unroll
        for (int v = 0; v < 8; v++){ acc0[v] = b11a; acc1[v] = b11b; }
        for (int k = 0; k < 64; k++){
            float w0 = W11s[k*C1 + lane];
            float w1 = (lane < 6) ? W11s[k*C1 + 64 + lane] : 0.f;
            const float4* ap = (const float4*)&a1s[w][k*8];
            float4 a0 = ap[0], a1v = ap[1];
            acc0[0] = fmaf(a0.x,  w0, acc0[0]); acc0[1] = fmaf(a0.y,  w0, acc0[1]);
            acc0[2] = fmaf(a0.z,  w0, acc0[2]); acc0[3] = fmaf(a0.w,  w0, acc0[3]);
            acc0[4] = fmaf(a1v.x, w0, acc0[4]); acc0[5] = fmaf(a1v.y, w0, acc0[5]);
            acc0[6] = fmaf(a1v.z, w0, acc0[6]); acc0[7] = fmaf(a1v.w, w0, acc0[7]);
            acc1[0] = fmaf(a0.x,  w1, acc1[0]); acc1[1] = fmaf(a0.y,  w1, acc1[1]);
            acc1[2] = fmaf(a0.z,  w1, acc1[2]); acc1[3] = fmaf(a0.w,  w1, acc1[3]);
            acc1[4] = fmaf(a1v.x, w1, acc1[4]); acc1[5] = fmaf(a1v.y, w1, acc1[5]);
            acc1[6] = fmaf(a1v.z, w1, acc1[6]); acc1[7] = fmaf(a1v.w, w1, acc1[7]);
        }
        float out0, out1;
        {
            float p[8];
#pragma unroll
            for (int v = 0; v < 8; v++) p[v] = gf0 * acc0[v];
            float m = p[0];
#pragma unroll
            for (int v = 1; v < 8; v++) m = fmaxf(m, p[v]);
            float den = 0.f, num = 0.f;
#pragma unroll
            for (int v = 0; v < 8; v++){ float e = __expf(p[v]-m); den += e; num = fmaf(e, p[v], num); }
            out0 = num / den;
        }
        {
            float p[8];
#pragma unroll
            for (int v = 0; v < 8; v++) p[v] = gf1 * acc1[v];
            float m = p[0];
#pragma unroll
            for (int v = 1; v < 8; v++) m = fmaxf(m, p[v]);
            float den = 0.f, num = 0.f;
#pragma unroll
            for (int v = 0; v < 8; v++){ float e = __expf(p[v]-m); den += e; num = fmaf(e, p[v], num); }
            out1 = num / den;
        }
        const bool msk = (id < 0);
        agg[(size_t)row*C1 + lane] = msk ? 0.f : out0;
        if (lane < 6) agg[(size_t)row*C1 + 64 + lane] = msk ? 0.f : out1;
        __syncthreads();
    }
}

// ---------------- BN2 stats ----------------
__global__ __launch_bounds__(256) void bn2_stats(const float* __restrict__ agg,
        const void* __restrict__ w20, const void* __restrict__ b20, double* __restrict__ sums,
        const int* __restrict__ flag){
    __shared__ float W[C1*128];
    __shared__ double red[256];
    const bool F = (*flag != 0);
    const int t = threadIdx.x;
    for (int e = t; e < C1*128; e += 256) W[e] = ld(w20, e, F);
    __syncthreads();
    const int c = t & 127, h = t >> 7;
    const float bz = ld(b20, c, F);
    double s = 0.0, q = 0.0;
    const int rbase = blockIdx.x * 512;
    for (int i = 0; i < 256; i++){
        const float* ar = agg + (size_t)(rbase + 2*i + h)*C1;
        float z = bz;
        for (int k = 0; k < C1; k++) z = fmaf(ar[k], W[k*128+c], z);
        s += (double)z; q += (double)z * (double)z;
    }
    red[t] = s; __syncthreads();
    double sTot = (h == 0) ? red[t] + red[t+128] : 0.0;
    __syncthreads();
    red[t] = q; __syncthreads();
    if (h == 0){
        double qTot = red[t] + red[t+128];
        atomicAdd(&sums[c], sTot);
        atomicAdd(&sums[128+c], qTot);
    }
}

// ---------------- BN2 finalize ----------------
__global__ void bn2_final(const double* __restrict__ sums, const void* __restrict__ g2,
        const void* __restrict__ bt2, float* __restrict__ bn2, const int* __restrict__ flag){
    const bool F = (*flag != 0);
    int t = threadIdx.x; // 128
    const double K = 131072.0;
    double mean = sums[t] / K;
    double var = sums[128+t] / K - mean*mean;
    float sc = ld(g2, t, F) / sqrtf((float)var + 1e-5f);
    bn2[t] = sc;
    bn2[128+t] = ld(bt2, t, F) - (float)mean * sc;
}

// ---------------- m2 + residual + gelu + max over ns ----------------
__global__ __launch_bounds__(128) void final_kernel(
        const float* __restrict__ agg, const void* __restrict__ f, const int* __restrict__ idx,
        const void* __restrict__ w20, const void* __restrict__ b20, const float* __restrict__ bn2,
        const void* __restrict__ w21, const void* __restrict__ b21,
        const void* __restrict__ rw, const void* __restrict__ rb,
        void* __restrict__ out, const int* __restrict__ flag){
    __shared__ float aggT[C1*36];   // [k][ns], pad 36
    __shared__ float gfs[64*36];
    __shared__ float wmids[128*36];
    const bool F = (*flag != 0);
    const int g = blockIdx.x, t = threadIdx.x;
    const int b = g >> 10;
    const int rowbase = g * KNS;
    for (int e = t; e < C1*KNS; e += 128){
        int ns = e / C1, k = e - ns*C1;
        aggT[k*36+ns] = agg[(size_t)(rowbase+ns)*C1 + k];
    }
    for (int e = t; e < 64*KNS; e += 128){
        int ns = e >> 6, k = e & 63;
        int id = idx[rowbase+ns];
        gfs[k*36+ns] = (id >= 0) ? ld(f, (size_t)(b*NN+id)*64 + k, F) : 0.f;
    }
    __syncthreads();
    float acc[32];
    {
        const float bz = ld(b20, t, F);
#pragma unroll
        for (int ns = 0; ns < 32; ns++) acc[ns] = bz;
        for (int k = 0; k < C1; k++){
            const float wv = ld(w20, k*128+t, F);
            const float4* ap = (const float4*)&aggT[k*36];
#pragma unroll
            for (int q = 0; q < 8; q++){
                float4 a = ap[q];
                acc[q*4+0] = fmaf(a.x, wv, acc[q*4+0]);
                acc[q*4+1] = fmaf(a.y, wv, acc[q*4+1]);
                acc[q*4+2] = fmaf(a.z, wv, acc[q*4+2]);
                acc[q*4+3] = fmaf(a.w, wv, acc[q*4+3]);
            }
        }
    }
    const float sc2 = bn2[t], sh2 = bn2[128+t];
#pragma unroll
    for (int ns = 0; ns < 32; ns++) wmids[t*36+ns] = fmaxf(fmaf(acc[ns], sc2, sh2), 0.f);
    __syncthreads();
    float acc2[32];
    const float bo = ld(b21, t, F) + ld(rb, t, F);
#pragma unroll
    for (int ns = 0; ns < 32; ns++) acc2[ns] = bo;
    for (int k = 0; k < 128; k++){
        const float wv = ld(w21, k*128+t, F);
        const float4* wp = (const float4*)&wmids[k*36];
#pragma unroll
        for (int q = 0; q < 8; q++){
            float4 a = wp[q];
            acc2[q*4+0] = fmaf(a.x, wv, acc2[q*4+0]);
            acc2[q*4+1] = fmaf(a.y, wv, acc2[q*4+1]);
            acc2[q*4+2] = fmaf(a.z, wv, acc2[q*4+2]);
            acc2[q*4+3] = fmaf(a.w, wv, acc2[q*4+3]);
        }
    }
    for (int k = 0; k < 64; k++){
        const float wv = ld(rw, k*128+t, F);
        const float4* gp = (const float4*)&gfs[k*36];
#pragma unroll
        for (int q = 0; q < 8; q++){
            float4 a = gp[q];
            acc2[q*4+0] = fmaf(a.x, wv, acc2[q*4+0]);
            acc2[q*4+1] = fmaf(a.y, wv, acc2[q*4+1]);
            acc2[q*4+2] = fmaf(a.z, wv, acc2[q*4+2]);
            acc2[q*4+3] = fmaf(a.w, wv, acc2[q*4+3]);
        }
    }
    float mx = -3.4e38f;
#pragma unroll
    for (int ns = 0; ns < 32; ns++){
        float x = acc2[ns];
        float y = 0.5f * x * (1.f + erff(x * 0.70710678118654752f));
        mx = fmaxf(mx, y);
    }
    st(out, (size_t)g*128 + t, mx, F);
}

extern "C" void kernel_launch(void* const* d_in, const int* in_sizes, int n_in,
                              void* d_out, int out_size, void* d_ws, size_t ws_size,
                              hipStream_t stream){
    const void* xyz = d_in[0];
    const void* f   = d_in[1];
    const void* fpt = d_in[2];
    const void* w10 = d_in[3];
    const void* b10 = d_in[4];
    const void* g1  = d_in[5];
    const void* bt1 = d_in[6];
    const void* w11 = d_in[7];
    const void* b11 = d_in[8];
    const void* w20 = d_in[9];
    const void* b20 = d_in[10];
    const void* g2  = d_in[11];
    const void* bt2 = d_in[12];
    const void* w21 = d_in[13];
    const void* b21 = d_in[14];
    const void* rw  = d_in[15];
    const void* rb  = d_in[16];

    char* ws = (char*)d_ws;
    float*  nxf  = (float*) (ws + 0);         // B*S*3 f32
    int*    idx  = (int*)   (ws + 65536);     // B*S*32 i32
    double* M    = (double*)(ws + 655360);    // 105 f64 moments
    float*  bn1  = (float*) (ws + 786432);    // 128 f32
    double* sums = (double*)(ws + 917504);    // 256 f64
    float*  bn2  = (float*) (ws + 1048576);   // 256 f32
    int*    flag = (int*)   (ws + 1050624);   // dtype flag
    float*  agg  = (float*) (ws + 2097152);   // 131072*70 f32 (36.7 MB)

    init_kernel<<<1, 256, 0, stream>>>(xyz, M, sums, flag);
    fps_kernel<<<4, 512, 0, stream>>>(xyz, nxf, d_out, flag);
    ball_kernel<<<dim3(4,4), 256, 0, stream>>>(xyz, nxf, idx, flag);
    bn1_stats<<<1024, 128, 0, stream>>>(xyz, idx, fpt, M, flag);
    bn1_final<<<1, 128, 0, stream>>>(M, w10, b10, g1, bt1, bn1, flag);
    m1_kernel<<<512, 256, 0, stream>>>(xyz, f, fpt, w10, b10, w11, b11, nxf, idx, bn1, agg, flag);
    bn2_stats<<<256, 256, 0, stream>>>(agg, w20, b20, sums, flag);
    bn2_final<<<1, 128, 0, stream>>>(sums, g2, bt2, bn2, flag);
    final_kernel<<<4096, 128, 0, stream>>>(agg, f, idx, w20, b20, bn2, w21, b21, rw, rb, d_out, flag);
}

// Round 3
// 2600.276 us; speedup vs baseline: 1.2155x; 1.2155x over previous
//
#include <hip/hip_runtime.h>
#include <hip/hip_bf16.h>
#include <math.h>

typedef __hip_bfloat16 bf16;

#define BB  4
#define NN  4096
#define SS  1024
#define KNS 32
#define C1  70

__device__ __forceinline__ float b2f(bf16 x){ return __bfloat162float(x); }

__device__ __forceinline__ float ld(const void* p, size_t i, bool F){
    return F ? ((const float*)p)[i] : __bfloat162float(((const bf16*)p)[i]);
}
__device__ __forceinline__ void st(void* p, size_t i, float v, bool F){
    if (F) ((float*)p)[i] = v; else ((bf16*)p)[i] = __float2bfloat16(v);
}

// ---------------- init: dtype detect + zero stats ----------------
__global__ void init_kernel(const void* xyz, double* __restrict__ M,
                            double* __restrict__ sums, int* __restrict__ flag){
    __shared__ int cnt;
    const int t = threadIdx.x;
    if (t == 0) cnt = 0;
    if (t < 105) M[t] = 0.0;
    if (t < 256) sums[t] = 0.0;
    __syncthreads();
    int c = 0;
    for (int i = t; i < 2048; i += 256){
        float v = __bfloat162float(((const bf16*)xyz)[i]);
        if (!(fabsf(v) <= 1.5f)) c++;   // catches NaN too
    }
    atomicAdd(&cnt, c);
    __syncthreads();
    if (t == 0) *flag = (cnt > 10) ? 1 : 0;
}

// ---------------- FPS v2: coords in registers, 1 barrier/iter ----------------
__global__ __launch_bounds__(256) void fps_kernel(const void* __restrict__ xyz,
        float* __restrict__ nxf, void* __restrict__ out, const int* __restrict__ flag){
    __shared__ float4 pts[NN];     // 64 KB, read-only after staging
    __shared__ int sidx[SS];
    __shared__ float srv[2][4];
    __shared__ int   sri[2][4];
    const bool F = (*flag != 0);
    const int b = blockIdx.x, t = threadIdx.x, lane = t & 63, w = t >> 6;
    float px[16], py[16], pz[16], mind[16];
#pragma unroll
    for (int j = 0; j < 16; j++){
        int i = j*256 + t;
        float X = ld(xyz, (size_t)(b*NN+i)*3+0, F);
        float Y = ld(xyz, (size_t)(b*NN+i)*3+1, F);
        float Z = ld(xyz, (size_t)(b*NN+i)*3+2, F);
        px[j] = X; py[j] = Y; pz[j] = Z; mind[j] = 1e10f;
        pts[i] = make_float4(X, Y, Z, 0.f);
    }
    if (t == 0) sidx[0] = 0;
    __syncthreads();
    float4 q = pts[0];
    for (int s = 1; s < SS; s++){
        float bd = -1.f; int bi = 0;
#pragma unroll
        for (int j = 0; j < 16; j++){
            float dx = __fsub_rn(px[j], q.x);
            float dy = __fsub_rn(py[j], q.y);
            float dz = __fsub_rn(pz[j], q.z);
            float d  = __fadd_rn(__fadd_rn(__fmul_rn(dx,dx), __fmul_rn(dy,dy)), __fmul_rn(dz,dz));
            float m = fminf(mind[j], d); mind[j] = m;
            if (m > bd){ bd = m; bi = j*256 + t; }   // ascending index -> strict > keeps first
        }
#pragma unroll
        for (int off = 1; off < 64; off <<= 1){
            float ov = __shfl_xor(bd, off);
            int   oi = __shfl_xor(bi, off);
            if (ov > bd || (ov == bd && oi < bi)){ bd = ov; bi = oi; }
        }
        const int par = s & 1;
        if (lane == 0){ srv[par][w] = bd; sri[par][w] = bi; }
        __syncthreads();
        float v = srv[par][0]; int ix = sri[par][0];
#pragma unroll
        for (int k = 1; k < 4; k++){
            float ov = srv[par][k]; int oi = sri[par][k];
            if (ov > v || (ov == v && oi < ix)){ v = ov; ix = oi; }
        }
        if (t == 0) sidx[s] = ix;
        q = pts[ix];
    }
    __syncthreads();
    const size_t o1 = (size_t)BB*SS*128;
    for (int s2 = t; s2 < SS; s2 += 256){
        int i = sidx[s2];
        float4 p = pts[i];
        nxf[(b*SS+s2)*3+0] = p.x; nxf[(b*SS+s2)*3+1] = p.y; nxf[(b*SS+s2)*3+2] = p.z;
        st(out, o1 + (size_t)(b*SS+s2)*3+0, p.x, F);
        st(out, o1 + (size_t)(b*SS+s2)*3+1, p.y, F);
        st(out, o1 + (size_t)(b*SS+s2)*3+2, p.z, F);
    }
}

// ---------------- ball query ----------------
__global__ __launch_bounds__(256) void ball_kernel(const void* __restrict__ xyz,
        const float* __restrict__ nxf, int* __restrict__ idx, const int* __restrict__ flag){
    __shared__ float sx[NN], sy[NN], sz[NN];
    const bool F = (*flag != 0);
    const int b = blockIdx.x, t = threadIdx.x;
    for (int i = t; i < NN; i += 256){
        sx[i] = ld(xyz, (size_t)(b*NN+i)*3+0, F);
        sy[i] = ld(xyz, (size_t)(b*NN+i)*3+1, F);
        sz[i] = ld(xyz, (size_t)(b*NN+i)*3+2, F);
    }
    __syncthreads();
    const int s = blockIdx.y*256 + t;
    const float px = nxf[(b*SS+s)*3+0];
    const float py = nxf[(b*SS+s)*3+1];
    const float pz = nxf[(b*SS+s)*3+2];
    const float R2 = 0.2f*0.2f;
    int* op = idx + (size_t)(b*SS+s)*KNS;
    int cnt = 0;
    for (int i = 0; i < NN; i++){
        float dx = __fsub_rn(px, sx[i]);
        float dy = __fsub_rn(py, sy[i]);
        float dz = __fsub_rn(pz, sz[i]);
        float d2 = __fadd_rn(__fadd_rn(__fmul_rn(dx,dx), __fmul_rn(dy,dy)), __fmul_rn(dz,dz));
        if (d2 < R2){
            op[cnt++] = i;
            if (cnt == KNS) break;
        }
    }
    for (; cnt < KNS; cnt++) op[cnt] = -1;
}

// ---------------- BN1 stats: 14x14 moment matrix of extended coc ----------------
__global__ __launch_bounds__(128) void bn1_stats(const void* __restrict__ xyz,
        const int* __restrict__ idx, const void* __restrict__ fpt, double* __restrict__ M,
        const int* __restrict__ flag){
    __shared__ float cs[128][14];
    const bool F = (*flag != 0);
    const int t = threadIdx.x;
    int ci = 0, cj = 0;
    if (t < 105){
        int e = t, i = 0, off = 0;
        while (e - off >= 14 - i){ off += 14 - i; i++; }
        ci = i; cj = i + (e - off);
    }
    float fx[8], fy[8], fz[8];
#pragma unroll
    for (int v = 0; v < 8; v++){
        fx[v] = ld(fpt, v*3+0, F); fy[v] = ld(fpt, v*3+1, F); fz[v] = ld(fpt, v*3+2, F);
    }
    double acc = 0.0;
    const int base = blockIdx.x * 1024;
    for (int st8 = 0; st8 < 8; st8++){
        int e = base + st8*128 + t;
        int row = e >> 3, v = e & 7;
        int b = row >> 15;
        int id = idx[row];
        float gx = 0.f, gy = 0.f, gz = 0.f;
        if (id >= 0){
            gx = ld(xyz, (size_t)(b*NN+id)*3+0, F);
            gy = ld(xyz, (size_t)(b*NN+id)*3+1, F);
            gz = ld(xyz, (size_t)(b*NN+id)*3+2, F);
        }
        float ax = gx - fx[v], ay = gy - fy[v], az = gz - fz[v];
        float eu = sqrtf(ax*ax + ay*ay + az*az);
        cs[t][0] = -ax; cs[t][1] = -ay; cs[t][2] = -az;
        cs[t][3] =  ax; cs[t][4] =  ay; cs[t][5] =  az;
        cs[t][6] = eu;  cs[t][7] = gx;  cs[t][8] = gy; cs[t][9] = gz;
        cs[t][10] = fx[v]; cs[t][11] = fy[v]; cs[t][12] = fz[v]; cs[t][13] = 1.0f;
        __syncthreads();
        if (t < 105){
            float p = 0.f;
            for (int u = 0; u < 128; u++) p = fmaf(cs[u][ci], cs[u][cj], p);
            acc += (double)p;
        }
        __syncthreads();
    }
    if (t < 105) atomicAdd(&M[t], acc);
}

// ---------------- BN1 finalize ----------------
__global__ __launch_bounds__(128) void bn1_final(const double* __restrict__ M,
        const void* __restrict__ w10, const void* __restrict__ b10,
        const void* __restrict__ g1, const void* __restrict__ bt1, float* __restrict__ bn1,
        const int* __restrict__ flag){
    __shared__ double Mm[14][14];
    __shared__ double mv[14];
    const bool F = (*flag != 0);
    const int t = threadIdx.x;
    if (t < 105){
        int e = t, i = 0, off = 0;
        while (e - off >= 14 - i){ off += 14 - i; i++; }
        int j = i + (e - off);
        double val = M[t];
        Mm[i][j] = val; Mm[j][i] = val;
    }
    __syncthreads();
    const double K = 1048576.0;
    if (t < 14) mv[t] = Mm[t][13] / K;
    __syncthreads();
    if (t < 64){
        double wc[13];
        for (int i = 0; i < 13; i++) wc[i] = (double)ld(w10, i*64+t, F);
        double mean = (double)ld(b10, t, F);
        for (int i = 0; i < 13; i++) mean += mv[i]*wc[i];
        double var = 0.0;
        for (int i = 0; i < 13; i++)
            for (int j = 0; j < 13; j++)
                var += wc[i]*wc[j]*(Mm[i][j]/K - mv[i]*mv[j]);
        float sc = ld(g1, t, F) / sqrtf((float)var + 1e-5f);
        bn1[t] = sc;
        bn1[64+t] = ld(bt1, t, F) - (float)mean * sc;
    }
}

// ---------------- m1 MLP + frame softmax attention ----------------
__global__ __launch_bounds__(256) void m1_kernel(
        const void* __restrict__ xyz, const void* __restrict__ f, const void* __restrict__ fpt,
        const void* __restrict__ w10, const void* __restrict__ b10,
        const void* __restrict__ w11, const void* __restrict__ b11,
        const float* __restrict__ nxf, const int* __restrict__ idx,
        const float* __restrict__ bn1, float* __restrict__ agg, const int* __restrict__ flag){
    __shared__ float W11s[64*C1];
    __shared__ float a1s[4][512];
    const bool F = (*flag != 0);
    const int t = threadIdx.x, lane = t & 63, w = t >> 6;
    for (int e = t; e < 64*C1; e += 256) W11s[e] = ld(w11, e, F);
    float W10c[13];
#pragma unroll
    for (int i = 0; i < 13; i++) W10c[i] = ld(w10, i*64+lane, F);
    const float b10v = ld(b10, lane, F);
    const float sc1 = bn1[lane], sh1 = bn1[64+lane];
    const float b11a = ld(b11, lane, F);
    const float b11b = (lane < 6) ? ld(b11, 64+lane, F) : 0.f;
    float fx[8], fy[8], fz[8];
#pragma unroll
    for (int v = 0; v < 8; v++){
        fx[v] = ld(fpt, v*3+0, F); fy[v] = ld(fpt, v*3+1, F); fz[v] = ld(fpt, v*3+2, F);
    }
    __syncthreads();
    for (int it = 0; it < 64; it++){
        const int row = blockIdx.x*256 + it*4 + w;
        const int b = row >> 15, s = (row >> 5) & 1023;
        const int id = idx[row];
        float gx = 0.f, gy = 0.f, gz = 0.f, fv0 = 0.f, fv1 = 0.f;
        if (id >= 0){
            gx = ld(xyz, (size_t)(b*NN+id)*3+0, F);
            gy = ld(xyz, (size_t)(b*NN+id)*3+1, F);
            gz = ld(xyz, (size_t)(b*NN+id)*3+2, F);
            if (lane >= 6) fv0 = ld(f, (size_t)(b*NN+id)*64 + (lane-6), F);
            if (lane < 6)  fv1 = ld(f, (size_t)(b*NN+id)*64 + (58+lane), F);
        }
        const float nxx = nxf[(b*SS+s)*3+0], nxy = nxf[(b*SS+s)*3+1], nxz = nxf[(b*SS+s)*3+2];
        float gf0;
        if (lane == 0) gf0 = gx; else if (lane == 1) gf0 = gy; else if (lane == 2) gf0 = gz;
        else if (lane == 3) gf0 = gx - nxx; else if (lane == 4) gf0 = gy - nxy;
        else if (lane == 5) gf0 = gz - nxz; else gf0 = fv0;
        const float gf1 = fv1;
#pragma unroll
        for (int v = 0; v < 8; v++){
            float ax = gx - fx[v], ay = gy - fy[v], az = gz - fz[v];
            float eu = sqrtf(ax*ax + ay*ay + az*az);
            float z = b10v;
            z = fmaf(-ax, W10c[0], z); z = fmaf(-ay, W10c[1], z); z = fmaf(-az, W10c[2], z);
            z = fmaf( ax, W10c[3], z); z = fmaf( ay, W10c[4], z); z = fmaf( az, W10c[5], z);
            z = fmaf( eu, W10c[6], z);
            z = fmaf( gx, W10c[7], z); z = fmaf( gy, W10c[8], z); z = fmaf( gz, W10c[9], z);
            z = fmaf(fx[v], W10c[10], z); z = fmaf(fy[v], W10c[11], z); z = fmaf(fz[v], W10c[12], z);
            float a1 = fmaxf(fmaf(z, sc1, sh1), 0.f);
            a1s[w][lane*8+v] = a1;
        }
        __syncthreads();
        float acc0[8], acc1[8];
#pragma unroll
        for (int v = 0; v < 8; v++){ acc0[v] = b11a; acc1[v] = b11b; }
        for (int k = 0; k < 64; k++){
            float w0 = W11s[k*C1 + lane];
            float w1 = (lane < 6) ? W11s[k*C1 + 64 + lane] : 0.f;
            const float4* ap = (const float4*)&a1s[w][k*8];
            float4 a0 = ap[0], a1v = ap[1];
            acc0[0] = fmaf(a0.x,  w0, acc0[0]); acc0[1] = fmaf(a0.y,  w0, acc0[1]);
            acc0[2] = fmaf(a0.z,  w0, acc0[2]); acc0[3] = fmaf(a0.w,  w0, acc0[3]);
            acc0[4] = fmaf(a1v.x, w0, acc0[4]); acc0[5] = fmaf(a1v.y, w0, acc0[5]);
            acc0[6] = fmaf(a1v.z, w0, acc0[6]); acc0[7] = fmaf(a1v.w, w0, acc0[7]);
            acc1[0] = fmaf(a0.x,  w1, acc1[0]); acc1[1] = fmaf(a0.y,  w1, acc1[1]);
            acc1[2] = fmaf(a0.z,  w1, acc1[2]); acc1[3] = fmaf(a0.w,  w1, acc1[3]);
            acc1[4] = fmaf(a1v.x, w1, acc1[4]); acc1[5] = fmaf(a1v.y, w1, acc1[5]);
            acc1[6] = fmaf(a1v.z, w1, acc1[6]); acc1[7] = fmaf(a1v.w, w1, acc1[7]);
        }
        float out0, out1;
        {
            float p[8];
#pragma unroll
            for (int v = 0; v < 8; v++) p[v] = gf0 * acc0[v];
            float m = p[0];
#pragma unroll
            for (int v = 1; v < 8; v++) m = fmaxf(m, p[v]);
            float den = 0.f, num = 0.f;
#pragma unroll
            for (int v = 0; v < 8; v++){ float e = __expf(p[v]-m); den += e; num = fmaf(e, p[v], num); }
            out0 = num / den;
        }
        {
            float p[8];
#pragma unroll
            for (int v = 0; v < 8; v++) p[v] = gf1 * acc1[v];
            float m = p[0];
#pragma unroll
            for (int v = 1; v < 8; v++) m = fmaxf(m, p[v]);
            float den = 0.f, num = 0.f;
#pragma unroll
            for (int v = 0; v < 8; v++){ float e = __expf(p[v]-m); den += e; num = fmaf(e, p[v], num); }
            out1 = num / den;
        }
        const bool msk = (id < 0);
        agg[(size_t)row*C1 + lane] = msk ? 0.f : out0;
        if (lane < 6) agg[(size_t)row*C1 + 64 + lane] = msk ? 0.f : out1;
        __syncthreads();
    }
}

// ---------------- BN2 stats ----------------
__global__ __launch_bounds__(256) void bn2_stats(const float* __restrict__ agg,
        const void* __restrict__ w20, const void* __restrict__ b20, double* __restrict__ sums,
        const int* __restrict__ flag){
    __shared__ float W[C1*128];
    __shared__ double red[256];
    const bool F = (*flag != 0);
    const int t = threadIdx.x;
    for (int e = t; e < C1*128; e += 256) W[e] = ld(w20, e, F);
    __syncthreads();
    const int c = t & 127, h = t >> 7;
    const float bz = ld(b20, c, F);
    double s = 0.0, q = 0.0;
    const int rbase = blockIdx.x * 512;
    for (int i = 0; i < 256; i++){
        const float* ar = agg + (size_t)(rbase + 2*i + h)*C1;
        float z = bz;
        for (int k = 0; k < C1; k++) z = fmaf(ar[k], W[k*128+c], z);
        s += (double)z; q += (double)z * (double)z;
    }
    red[t] = s; __syncthreads();
    double sTot = (h == 0) ? red[t] + red[t+128] : 0.0;
    __syncthreads();
    red[t] = q; __syncthreads();
    if (h == 0){
        double qTot = red[t] + red[t+128];
        atomicAdd(&sums[c], sTot);
        atomicAdd(&sums[128+c], qTot);
    }
}

// ---------------- BN2 finalize ----------------
__global__ void bn2_final(const double* __restrict__ sums, const void* __restrict__ g2,
        const void* __restrict__ bt2, float* __restrict__ bn2, const int* __restrict__ flag){
    const bool F = (*flag != 0);
    int t = threadIdx.x; // 128
    const double K = 131072.0;
    double mean = sums[t] / K;
    double var = sums[128+t] / K - mean*mean;
    float sc = ld(g2, t, F) / sqrtf((float)var + 1e-5f);
    bn2[t] = sc;
    bn2[128+t] = ld(bt2, t, F) - (float)mean * sc;
}

// ---------------- prep: f32 weights, BN2 folded into w20 ----------------
__global__ __launch_bounds__(256) void prep_kernel(
        const void* __restrict__ w20, const void* __restrict__ b20,
        const void* __restrict__ w21, const void* __restrict__ b21,
        const void* __restrict__ rw, const void* __restrict__ rb,
        const float* __restrict__ bn2,
        float* __restrict__ w20f, float* __restrict__ w21f, float* __restrict__ rwf,
        float* __restrict__ b20f, float* __restrict__ bof, const int* __restrict__ flag){
    const bool F = (*flag != 0);
    int e = blockIdx.x*256 + threadIdx.x;
    if (e < 8960){ w20f[e] = ld(w20, e, F) * bn2[e & 127]; return; }
    int e2 = e - 8960;
    if (e2 < 16384){ w21f[e2] = ld(w21, e2, F); return; }
    int e3 = e2 - 16384;
    if (e3 < 8192){ rwf[e3] = ld(rw, e3, F); return; }
    int e4 = e3 - 8192;
    if (e4 < 128){
        b20f[e4] = ld(b20, e4, F)*bn2[e4] + bn2[128+e4];
        bof[e4]  = ld(b21, e4, F) + ld(rb, e4, F);
    }
}

// ---------------- final v2: lane=(group,ns), regs=32 channels/wave ----------------
__global__ __launch_bounds__(256) void final_kernel(
        const float* __restrict__ agg, const void* __restrict__ f, const int* __restrict__ idx,
        const float* __restrict__ w20f, const float* __restrict__ b20f,
        const float* __restrict__ w21f, const float* __restrict__ rwf,
        const float* __restrict__ bof,
        void* __restrict__ out, const int* __restrict__ flag){
    __shared__ float aggT[70*65];    // [k][r], pad 65 -> conflict-free both ways
    __shared__ float gfs[64*65];     // [cin][r]
    __shared__ float wmids[128*64];  // [c][r]
    __shared__ float obuf[256];
    const bool F = (*flag != 0);
    const int t = threadIdx.x, lane = t & 63;
    const int wbase = __builtin_amdgcn_readfirstlane((t >> 6) << 5); // SGPR -> s_load weights
    const int rowbase = blockIdx.x * 64;      // 2 groups x 32 ns per block
    for (int e = t; e < 70*64; e += 256){
        int r = e / 70, k = e - r*70;
        aggT[k*65 + r] = agg[(size_t)rowbase*70 + e];   // coalesced global read
    }
    for (int e = t; e < 64*64; e += 256){
        int r = e >> 6, cin = e & 63;
        int id = idx[rowbase + r];
        int b = (rowbase + r) >> 15;
        gfs[cin*65 + r] = (id >= 0) ? ld(f, (size_t)(b*NN+id)*64 + cin, F) : 0.f;
    }
    __syncthreads();
    float acc[32];
#pragma unroll
    for (int j = 0; j < 32; j++) acc[j] = b20f[wbase + j];
#pragma unroll 2
    for (int k = 0; k < 70; k++){
        float av = aggT[k*65 + lane];
        const float* wr = w20f + k*128 + wbase;
#pragma unroll
        for (int j = 0; j < 32; j++) acc[j] = fmaf(av, wr[j], acc[j]);
    }
#pragma unroll
    for (int j = 0; j < 32; j++)
        wmids[(wbase + j)*64 + lane] = fmaxf(acc[j], 0.f);
    __syncthreads();
    float acc2[32];
#pragma unroll
    for (int j = 0; j < 32; j++) acc2[j] = bof[wbase + j];
#pragma unroll 2
    for (int k = 0; k < 128; k++){
        float wv = wmids[k*64 + lane];
        const float* wr = w21f + k*128 + wbase;
#pragma unroll
        for (int j = 0; j < 32; j++) acc2[j] = fmaf(wv, wr[j], acc2[j]);
    }
#pragma unroll 2
    for (int k = 0; k < 64; k++){
        float gv = gfs[k*65 + lane];
        const float* wr = rwf + k*128 + wbase;
#pragma unroll
        for (int j = 0; j < 32; j++) acc2[j] = fmaf(gv, wr[j], acc2[j]);
    }
    // gelu (exact erf) then max over ns within each 32-lane half
#pragma unroll
    for (int j = 0; j < 32; j++){
        float x = acc2[j];
        float y = 0.5f * x * (1.f + erff(x * 0.70710678118654752f));
#pragma unroll
        for (int off = 1; off < 32; off <<= 1)
            y = fmaxf(y, __shfl_xor(y, off));
        if ((lane & 31) == 0) obuf[(lane >> 5)*128 + wbase + j] = y;
    }
    __syncthreads();
    st(out, (size_t)blockIdx.x*256 + t, obuf[t], F);
}

extern "C" void kernel_launch(void* const* d_in, const int* in_sizes, int n_in,
                              void* d_out, int out_size, void* d_ws, size_t ws_size,
                              hipStream_t stream){
    const void* xyz = d_in[0];
    const void* f   = d_in[1];
    const void* fpt = d_in[2];
    const void* w10 = d_in[3];
    const void* b10 = d_in[4];
    const void* g1  = d_in[5];
    const void* bt1 = d_in[6];
    const void* w11 = d_in[7];
    const void* b11 = d_in[8];
    const void* w20 = d_in[9];
    const void* b20 = d_in[10];
    const void* g2  = d_in[11];
    const void* bt2 = d_in[12];
    const void* w21 = d_in[13];
    const void* b21 = d_in[14];
    const void* rw  = d_in[15];
    const void* rb  = d_in[16];

    char* ws = (char*)d_ws;
    float*  nxf  = (float*) (ws + 0);
    int*    idx  = (int*)   (ws + 65536);
    double* M    = (double*)(ws + 655360);
    float*  bn1  = (float*) (ws + 786432);
    double* sums = (double*)(ws + 917504);
    float*  bn2  = (float*) (ws + 1048576);
    int*    flag = (int*)   (ws + 1050624);
    float*  w20f = (float*) (ws + 1114112);   // 8960 f32
    float*  w21f = (float*) (ws + 1179648);   // 16384 f32
    float*  rwf  = (float*) (ws + 1245184);   // 8192 f32
    float*  b20f = (float*) (ws + 1277952);   // 128 f32
    float*  bof  = (float*) (ws + 1278464);   // 128 f32
    float*  agg  = (float*) (ws + 2097152);   // 131072*70 f32

    init_kernel<<<1, 256, 0, stream>>>(xyz, M, sums, flag);
    fps_kernel<<<4, 256, 0, stream>>>(xyz, nxf, d_out, flag);
    ball_kernel<<<dim3(4,4), 256, 0, stream>>>(xyz, nxf, idx, flag);
    bn1_stats<<<1024, 128, 0, stream>>>(xyz, idx, fpt, M, flag);
    bn1_final<<<1, 128, 0, stream>>>(M, w10, b10, g1, bt1, bn1, flag);
    m1_kernel<<<512, 256, 0, stream>>>(xyz, f, fpt, w10, b10, w11, b11, nxf, idx, bn1, agg, flag);
    bn2_stats<<<256, 256, 0, stream>>>(agg, w20, b20, sums, flag);
    bn2_final<<<1, 128, 0, stream>>>(sums, g2, bt2, bn2, flag);
    prep_kernel<<<132, 256, 0, stream>>>(w20, b20, w21, b21, rw, rb, bn2,
                                         w20f, w21f, rwf, b20f, bof, flag);
    final_kernel<<<2048, 256, 0, stream>>>(agg, f, idx, w20f, b20f, w21f, rwf, bof, d_out, flag);
}

// Round 4
// 1938.844 us; speedup vs baseline: 1.6302x; 1.3411x over previous
//
#include <hip/hip_runtime.h>
#include <hip/hip_bf16.h>
#include <math.h>

typedef __hip_bfloat16 bf16;
typedef __attribute__((ext_vector_type(8))) short short8;
typedef __attribute__((ext_vector_type(4))) float f32x4;

#define BB  4
#define NN  4096
#define SS  1024
#define KNS 32
#define C1  70

__device__ __forceinline__ float b2f(bf16 x){ return __bfloat162float(x); }

__device__ __forceinline__ float ld(const void* p, size_t i, bool F){
    return F ? ((const float*)p)[i] : __bfloat162float(((const bf16*)p)[i]);
}
__device__ __forceinline__ void st(void* p, size_t i, float v, bool F){
    if (F) ((float*)p)[i] = v; else ((bf16*)p)[i] = __float2bfloat16(v);
}
__device__ __forceinline__ unsigned short f2us(float x){
    __hip_bfloat16 h = __float2bfloat16(x);
    return *reinterpret_cast<unsigned short*>(&h);
}
__device__ __forceinline__ float us2f(unsigned short u){
    return __uint_as_float(((unsigned)u) << 16);
}

// ---------------- init: dtype detect + zero stats ----------------
__global__ void init_kernel(const void* xyz, double* __restrict__ M,
                            double* __restrict__ sums, int* __restrict__ flag){
    __shared__ int cnt;
    const int t = threadIdx.x;
    if (t == 0) cnt = 0;
    if (t < 105) M[t] = 0.0;
    if (t < 256) sums[t] = 0.0;
    __syncthreads();
    int c = 0;
    for (int i = t; i < 2048; i += 256){
        float v = __bfloat162float(((const bf16*)xyz)[i]);
        if (!(fabsf(v) <= 1.5f)) c++;   // catches NaN too
    }
    atomicAdd(&cnt, c);
    __syncthreads();
    if (t == 0) *flag = (cnt > 10) ? 1 : 0;
}

// ---------------- FPS: coords in registers, u64 packed reduce ----------------
__global__ __launch_bounds__(256) void fps_kernel(const void* __restrict__ xyz,
        float* __restrict__ nxf, void* __restrict__ out, const int* __restrict__ flag){
    __shared__ float4 pts[NN];     // 64 KB, read-only after staging
    __shared__ int sidx[SS];
    __shared__ unsigned long long skey[2][4];
    const bool F = (*flag != 0);
    const int b = blockIdx.x, t = threadIdx.x, lane = t & 63, w = t >> 6;
    float px[16], py[16], pz[16], mind[16];
#pragma unroll
    for (int j = 0; j < 16; j++){
        int i = j*256 + t;
        float X = ld(xyz, (size_t)(b*NN+i)*3+0, F);
        float Y = ld(xyz, (size_t)(b*NN+i)*3+1, F);
        float Z = ld(xyz, (size_t)(b*NN+i)*3+2, F);
        px[j] = X; py[j] = Y; pz[j] = Z; mind[j] = 1e10f;
        pts[i] = make_float4(X, Y, Z, 0.f);
    }
    if (t == 0) sidx[0] = 0;
    __syncthreads();
    float4 q = pts[0];
    for (int s = 1; s < SS; s++){
        float bd = -1.f; int bi = 0;
#pragma unroll
        for (int j = 0; j < 16; j++){
            float dx = __fsub_rn(px[j], q.x);
            float dy = __fsub_rn(py[j], q.y);
            float dz = __fsub_rn(pz[j], q.z);
            float d  = __fadd_rn(__fadd_rn(__fmul_rn(dx,dx), __fmul_rn(dy,dy)), __fmul_rn(dz,dz));
            float m = fminf(mind[j], d); mind[j] = m;
            if (m > bd){ bd = m; bi = j*256 + t; }   // ascending index -> strict > keeps first
        }
        // pack: max d, tie -> min index (d>=0 so float bits order as uint)
        unsigned long long key = ((unsigned long long)__float_as_uint(bd) << 32)
                               | (unsigned)(~bi);
#pragma unroll
        for (int off = 1; off < 64; off <<= 1){
            unsigned long long o = __shfl_xor(key, off);
            if (o > key) key = o;
        }
        const int par = s & 1;
        if (lane == 0) skey[par][w] = key;
        __syncthreads();
        unsigned long long k0 = skey[par][0], k1 = skey[par][1];
        unsigned long long k2 = skey[par][2], k3 = skey[par][3];
        if (k1 > k0) k0 = k1;
        if (k3 > k2) k2 = k3;
        if (k2 > k0) k0 = k2;
        int ix = (int)(~(unsigned)(k0 & 0xffffffffull));
        if (t == 0) sidx[s] = ix;
        q = pts[ix];
    }
    __syncthreads();
    const size_t o1 = (size_t)BB*SS*128;
    for (int s2 = t; s2 < SS; s2 += 256){
        int i = sidx[s2];
        float4 p = pts[i];
        nxf[(b*SS+s2)*3+0] = p.x; nxf[(b*SS+s2)*3+1] = p.y; nxf[(b*SS+s2)*3+2] = p.z;
        st(out, o1 + (size_t)(b*SS+s2)*3+0, p.x, F);
        st(out, o1 + (size_t)(b*SS+s2)*3+1, p.y, F);
        st(out, o1 + (size_t)(b*SS+s2)*3+2, p.z, F);
    }
}

// ---------------- ball query ----------------
__global__ __launch_bounds__(256) void ball_kernel(const void* __restrict__ xyz,
        const float* __restrict__ nxf, int* __restrict__ idx, const int* __restrict__ flag){
    __shared__ float sx[NN], sy[NN], sz[NN];
    const bool F = (*flag != 0);
    const int b = blockIdx.x, t = threadIdx.x;
    for (int i = t; i < NN; i += 256){
        sx[i] = ld(xyz, (size_t)(b*NN+i)*3+0, F);
        sy[i] = ld(xyz, (size_t)(b*NN+i)*3+1, F);
        sz[i] = ld(xyz, (size_t)(b*NN+i)*3+2, F);
    }
    __syncthreads();
    const int s = blockIdx.y*256 + t;
    const float px = nxf[(b*SS+s)*3+0];
    const float py = nxf[(b*SS+s)*3+1];
    const float pz = nxf[(b*SS+s)*3+2];
    const float R2 = 0.2f*0.2f;
    int* op = idx + (size_t)(b*SS+s)*KNS;
    int cnt = 0;
    for (int i = 0; i < NN; i++){
        float dx = __fsub_rn(px, sx[i]);
        float dy = __fsub_rn(py, sy[i]);
        float dz = __fsub_rn(pz, sz[i]);
        float d2 = __fadd_rn(__fadd_rn(__fmul_rn(dx,dx), __fmul_rn(dy,dy)), __fmul_rn(dz,dz));
        if (d2 < R2){
            op[cnt++] = i;
            if (cnt == KNS) break;
        }
    }
    for (; cnt < KNS; cnt++) op[cnt] = -1;
}

// ---------------- BN1 stats: 14x14 moment matrix of extended coc ----------------
__global__ __launch_bounds__(128) void bn1_stats(const void* __restrict__ xyz,
        const int* __restrict__ idx, const void* __restrict__ fpt, double* __restrict__ M,
        const int* __restrict__ flag){
    __shared__ float cs[128][14];
    const bool F = (*flag != 0);
    const int t = threadIdx.x;
    int ci = 0, cj = 0;
    if (t < 105){
        int e = t, i = 0, off = 0;
        while (e - off >= 14 - i){ off += 14 - i; i++; }
        ci = i; cj = i + (e - off);
    }
    float fx[8], fy[8], fz[8];
#pragma unroll
    for (int v = 0; v < 8; v++){
        fx[v] = ld(fpt, v*3+0, F); fy[v] = ld(fpt, v*3+1, F); fz[v] = ld(fpt, v*3+2, F);
    }
    double acc = 0.0;
    const int base = blockIdx.x * 1024;
    for (int st8 = 0; st8 < 8; st8++){
        int e = base + st8*128 + t;
        int row = e >> 3, v = e & 7;
        int b = row >> 15;
        int id = idx[row];
        float gx = 0.f, gy = 0.f, gz = 0.f;
        if (id >= 0){
            gx = ld(xyz, (size_t)(b*NN+id)*3+0, F);
            gy = ld(xyz, (size_t)(b*NN+id)*3+1, F);
            gz = ld(xyz, (size_t)(b*NN+id)*3+2, F);
        }
        float ax = gx - fx[v], ay = gy - fy[v], az = gz - fz[v];
        float eu = sqrtf(ax*ax + ay*ay + az*az);
        cs[t][0] = -ax; cs[t][1] = -ay; cs[t][2] = -az;
        cs[t][3] =  ax; cs[t][4] =  ay; cs[t][5] =  az;
        cs[t][6] = eu;  cs[t][7] = gx;  cs[t][8] = gy; cs[t][9] = gz;
        cs[t][10] = fx[v]; cs[t][11] = fy[v]; cs[t][12] = fz[v]; cs[t][13] = 1.0f;
        __syncthreads();
        if (t < 105){
            float p = 0.f;
            for (int u = 0; u < 128; u++) p = fmaf(cs[u][ci], cs[u][cj], p);
            acc += (double)p;
        }
        __syncthreads();
    }
    if (t < 105) atomicAdd(&M[t], acc);
}

// ---------------- BN1 finalize ----------------
__global__ __launch_bounds__(128) void bn1_final(const double* __restrict__ M,
        const void* __restrict__ w10, const void* __restrict__ b10,
        const void* __restrict__ g1, const void* __restrict__ bt1, float* __restrict__ bn1,
        const int* __restrict__ flag){
    __shared__ double Mm[14][14];
    __shared__ double mv[14];
    const bool F = (*flag != 0);
    const int t = threadIdx.x;
    if (t < 105){
        int e = t, i = 0, off = 0;
        while (e - off >= 14 - i){ off += 14 - i; i++; }
        int j = i + (e - off);
        double val = M[t];
        Mm[i][j] = val; Mm[j][i] = val;
    }
    __syncthreads();
    const double K = 1048576.0;
    if (t < 14) mv[t] = Mm[t][13] / K;
    __syncthreads();
    if (t < 64){
        double wc[13];
        for (int i = 0; i < 13; i++) wc[i] = (double)ld(w10, i*64+t, F);
        double mean = (double)ld(b10, t, F);
        for (int i = 0; i < 13; i++) mean += mv[i]*wc[i];
        double var = 0.0;
        for (int i = 0; i < 13; i++)
            for (int j = 0; j < 13; j++)
                var += wc[i]*wc[j]*(Mm[i][j]/K - mv[i]*mv[j]);
        float sc = ld(g1, t, F) / sqrtf((float)var + 1e-5f);
        bn1[t] = sc;
        bn1[64+t] = ld(bt1, t, F) - (float)mean * sc;
    }
}

// ---------------- m1 v3: MFMA phase B (3-pass bf16 hi/lo), per-wave pipeline ----------------
// Wave processes 2 rows/iter: M = 16 = (r<<3)|v, K = 64 hidden, N = 80 (70 pad).
__global__ __launch_bounds__(256) void m1_kernel(
        const void* __restrict__ xyz, const void* __restrict__ f, const void* __restrict__ fpt,
        const void* __restrict__ w10, const void* __restrict__ b10,
        const void* __restrict__ w11, const void* __restrict__ b11,
        const float* __restrict__ nxf, const int* __restrict__ idx,
        const float* __restrict__ bn1, float* __restrict__ agg, const int* __restrict__ flag){
    __shared__ short sthi[4*2*8*72];   // [wave][r][v][k pad72] bf16 hi
    __shared__ short stlo[4*2*8*72];   // bf16 lo
    __shared__ float gfb[4*2*80];      // [wave][r][c pad80]
    const bool F = (*flag != 0);
    const int t = threadIdx.x, lane = t & 63, w = t >> 6;
    const int kq = lane >> 4, cn = lane & 15;

    // B fragments (W11 hi/lo) in registers: lane holds B[k=ks*32+kq*8+j][n=nt*16+cn]
    short8 Bh[2][5], Bl[2][5];
#pragma unroll
    for (int ks = 0; ks < 2; ks++)
#pragma unroll
    for (int nt = 0; nt < 5; nt++){
        short8 bh, bl;
#pragma unroll
        for (int j = 0; j < 8; j++){
            int k = ks*32 + kq*8 + j;
            int c = nt*16 + cn;
            float wv = (c < C1) ? ld(w11, (size_t)k*C1 + c, F) : 0.f;
            unsigned short h = f2us(wv);
            unsigned short l2 = f2us(wv - us2f(h));
            bh[j] = (short)h; bl[j] = (short)l2;
        }
        Bh[ks][nt] = bh; Bl[ks][nt] = bl;
    }
    float binit[5];
#pragma unroll
    for (int nt = 0; nt < 5; nt++){
        int c = nt*16 + cn;
        binit[nt] = (c < C1) ? ld(b11, c, F) : 0.f;
    }
    // phase-A per-lane constants (lane = hidden channel)
    float W10c[13];
#pragma unroll
    for (int i = 0; i < 13; i++) W10c[i] = ld(w10, i*64+lane, F);
    const float b10v = ld(b10, lane, F);
    const float sc1 = bn1[lane], sh1 = bn1[64+lane];
    float fx[8], fy[8], fz[8];
#pragma unroll
    for (int v = 0; v < 8; v++){
        fx[v] = ld(fpt, v*3+0, F); fy[v] = ld(fpt, v*3+1, F); fz[v] = ld(fpt, v*3+2, F);
    }
    // epilogue lane roles
    const int quad = lane >> 4;
    const int rr = quad >> 1;          // which row of the pair
    const int hh = quad & 1;           // which v-half
    // A-frag LDS offset pieces (m = lane&15 -> rA, vA)
    const int mA = lane & 15;
    const int rA = mA >> 3, vA = mA & 7;

    const int wid = blockIdx.x*4 + w;
    for (int p = 0; p < 16; p++){
        const int rowbase = wid*32 + p*2;
        int ids[2];
#pragma unroll
        for (int r = 0; r < 2; r++){
            const int row = rowbase + r;
            const int b = row >> 15, s = (row >> 5) & 1023;
            const int id = idx[row];
            ids[r] = id;
            float gx = 0.f, gy = 0.f, gz = 0.f, fv0 = 0.f, fv1 = 0.f;
            if (id >= 0){
                gx = ld(xyz, (size_t)(b*NN+id)*3+0, F);
                gy = ld(xyz, (size_t)(b*NN+id)*3+1, F);
                gz = ld(xyz, (size_t)(b*NN+id)*3+2, F);
                if (lane >= 6) fv0 = ld(f, (size_t)(b*NN+id)*64 + (lane-6), F);
                if (lane < 6)  fv1 = ld(f, (size_t)(b*NN+id)*64 + (58+lane), F);
            }
            const float nxx = nxf[(b*SS+s)*3+0], nxy = nxf[(b*SS+s)*3+1], nxz = nxf[(b*SS+s)*3+2];
            float gf0;
            if (lane == 0) gf0 = gx; else if (lane == 1) gf0 = gy; else if (lane == 2) gf0 = gz;
            else if (lane == 3) gf0 = gx - nxx; else if (lane == 4) gf0 = gy - nxy;
            else if (lane == 5) gf0 = gz - nxz; else gf0 = fv0;
            gfb[w*160 + r*80 + lane] = gf0;
            if (lane < 6)       gfb[w*160 + r*80 + 64 + lane] = fv1;
            else if (lane < 16) gfb[w*160 + r*80 + 64 + lane] = 0.f;
            const int sb = ((w*2 + r)*8)*72 + lane;
#pragma unroll
            for (int v = 0; v < 8; v++){
                float ax = gx - fx[v], ay = gy - fy[v], az = gz - fz[v];
                float eu = sqrtf(ax*ax + ay*ay + az*az);
                float z = b10v;
                z = fmaf(-ax, W10c[0], z); z = fmaf(-ay, W10c[1], z); z = fmaf(-az, W10c[2], z);
                z = fmaf( ax, W10c[3], z); z = fmaf( ay, W10c[4], z); z = fmaf( az, W10c[5], z);
                z = fmaf( eu, W10c[6], z);
                z = fmaf( gx, W10c[7], z); z = fmaf( gy, W10c[8], z); z = fmaf( gz, W10c[9], z);
                z = fmaf(fx[v], W10c[10], z); z = fmaf(fy[v], W10c[11], z); z = fmaf(fz[v], W10c[12], z);
                float a1 = fmaxf(fmaf(z, sc1, sh1), 0.f);
                unsigned short h = f2us(a1);
                unsigned short l2 = f2us(a1 - us2f(h));
                sthi[sb + v*72] = (short)h;
                stlo[sb + v*72] = (short)l2;
            }
        }
        // phase B: 30 MFMA (3-pass hi/lo)
        f32x4 acc[5];
#pragma unroll
        for (int nt = 0; nt < 5; nt++){
            f32x4 a; a[0] = binit[nt]; a[1] = binit[nt]; a[2] = binit[nt]; a[3] = binit[nt];
            acc[nt] = a;
        }
        const int aoff = ((w*2 + rA)*8 + vA)*72 + kq*8;
#pragma unroll
        for (int ks = 0; ks < 2; ks++){
            short8 ahi = *(const short8*)&sthi[aoff + ks*32];
            short8 alo = *(const short8*)&stlo[aoff + ks*32];
#pragma unroll
            for (int nt = 0; nt < 5; nt++){
                acc[nt] = __builtin_amdgcn_mfma_f32_16x16x32_bf16(ahi, Bh[ks][nt], acc[nt], 0, 0, 0);
                acc[nt] = __builtin_amdgcn_mfma_f32_16x16x32_bf16(alo, Bh[ks][nt], acc[nt], 0, 0, 0);
                acc[nt] = __builtin_amdgcn_mfma_f32_16x16x32_bf16(ahi, Bl[ks][nt], acc[nt], 0, 0, 0);
            }
        }
        // epilogue: p = gf*a, softmax over 8 v (4 in-reg + partner via shfl_xor 16)
        const bool msk = ((rr == 0 ? ids[0] : ids[1]) < 0);
#pragma unroll
        for (int nt = 0; nt < 5; nt++){
            const int col = nt*16 + cn;
            float gfv = gfb[w*160 + rr*80 + col];
            f32x4 a = acc[nt];
            float p0 = a[0]*gfv, p1 = a[1]*gfv, p2 = a[2]*gfv, p3 = a[3]*gfv;
            float mx = fmaxf(fmaxf(p0, p1), fmaxf(p2, p3));
            mx = fmaxf(mx, __shfl_xor(mx, 16));
            float e0 = __expf(p0 - mx), e1 = __expf(p1 - mx);
            float e2 = __expf(p2 - mx), e3 = __expf(p3 - mx);
            float den4 = (e0 + e1) + (e2 + e3);
            float num4 = fmaf(e3, p3, fmaf(e2, p2, fmaf(e1, p1, e0*p0)));
            float den = den4 + __shfl_xor(den4, 16);
            float num = num4 + __shfl_xor(num4, 16);
            float outv = num / den;
            if (hh == 0 && col < C1){
                agg[(size_t)(rowbase + rr)*C1 + col] = msk ? 0.f : outv;
            }
        }
    }
}

// ---------------- BN2 stats ----------------
__global__ __launch_bounds__(256) void bn2_stats(const float* __restrict__ agg,
        const void* __restrict__ w20, const void* __restrict__ b20, double* __restrict__ sums,
        const int* __restrict__ flag){
    __shared__ float W[C1*128];
    __shared__ double red[256];
    const bool F = (*flag != 0);
    const int t = threadIdx.x;
    for (int e = t; e < C1*128; e += 256) W[e] = ld(w20, e, F);
    __syncthreads();
    const int c = t & 127, h = t >> 7;
    const float bz = ld(b20, c, F);
    double s = 0.0, q = 0.0;
    const int rbase = blockIdx.x * 512;
    for (int i = 0; i < 256; i++){
        const float* ar = agg + (size_t)(rbase + 2*i + h)*C1;
        float z = bz;
        for (int k = 0; k < C1; k++) z = fmaf(ar[k], W[k*128+c], z);
        s += (double)z; q += (double)z * (double)z;
    }
    red[t] = s; __syncthreads();
    double sTot = (h == 0) ? red[t] + red[t+128] : 0.0;
    __syncthreads();
    red[t] = q; __syncthreads();
    if (h == 0){
        double qTot = red[t] + red[t+128];
        atomicAdd(&sums[c], sTot);
        atomicAdd(&sums[128+c], qTot);
    }
}

// ---------------- BN2 finalize ----------------
__global__ void bn2_final(const double* __restrict__ sums, const void* __restrict__ g2,
        const void* __restrict__ bt2, float* __restrict__ bn2, const int* __restrict__ flag){
    const bool F = (*flag != 0);
    int t = threadIdx.x; // 128
    const double K = 131072.0;
    double mean = sums[t] / K;
    double var = sums[128+t] / K - mean*mean;
    float sc = ld(g2, t, F) / sqrtf((float)var + 1e-5f);
    bn2[t] = sc;
    bn2[128+t] = ld(bt2, t, F) - (float)mean * sc;
}

// ---------------- prep: f32 weights, BN2 folded into w20 ----------------
__global__ __launch_bounds__(256) void prep_kernel(
        const void* __restrict__ w20, const void* __restrict__ b20,
        const void* __restrict__ w21, const void* __restrict__ b21,
        const void* __restrict__ rw, const void* __restrict__ rb,
        const float* __restrict__ bn2,
        float* __restrict__ w20f, float* __restrict__ w21f, float* __restrict__ rwf,
        float* __restrict__ b20f, float* __restrict__ bof, const int* __restrict__ flag){
    const bool F = (*flag != 0);
    int e = blockIdx.x*256 + threadIdx.x;
    if (e < 8960){ w20f[e] = ld(w20, e, F) * bn2[e & 127]; return; }
    int e2 = e - 8960;
    if (e2 < 16384){ w21f[e2] = ld(w21, e2, F); return; }
    int e3 = e2 - 16384;
    if (e3 < 8192){ rwf[e3] = ld(rw, e3, F); return; }
    int e4 = e3 - 8192;
    if (e4 < 128){
        b20f[e4] = ld(b20, e4, F)*bn2[e4] + bn2[128+e4];
        bof[e4]  = ld(b21, e4, F) + ld(rb, e4, F);
    }
}

// ---------------- final: lane=(group,ns), regs=32 channels/wave ----------------
__global__ __launch_bounds__(256) void final_kernel(
        const float* __restrict__ agg, const void* __restrict__ f, const int* __restrict__ idx,
        const float* __restrict__ w20f, const float* __restrict__ b20f,
        const float* __restrict__ w21f, const float* __restrict__ rwf,
        const float* __restrict__ bof,
        void* __restrict__ out, const int* __restrict__ flag){
    __shared__ float aggT[70*65];    // [k][r], pad 65
    __shared__ float gfs[64*65];     // [cin][r]
    __shared__ float wmids[128*64];  // [c][r]
    __shared__ float obuf[256];
    const bool F = (*flag != 0);
    const int t = threadIdx.x, lane = t & 63;
    const int wbase = __builtin_amdgcn_readfirstlane((t >> 6) << 5);
    const int rowbase = blockIdx.x * 64;
    for (int e = t; e < 70*64; e += 256){
        int r = e / 70, k = e - r*70;
        aggT[k*65 + r] = agg[(size_t)rowbase*70 + e];
    }
    for (int e = t; e < 64*64; e += 256){
        int r = e >> 6, cin = e & 63;
        int id = idx[rowbase + r];
        int b = (rowbase + r) >> 15;
        gfs[cin*65 + r] = (id >= 0) ? ld(f, (size_t)(b*NN+id)*64 + cin, F) : 0.f;
    }
    __syncthreads();
    float acc[32];
#pragma unroll
    for (int j = 0; j < 32; j++) acc[j] = b20f[wbase + j];
#pragma unroll 2
    for (int k = 0; k < 70; k++){
        float av = aggT[k*65 + lane];
        const float* wr = w20f + k*128 + wbase;
#pragma unroll
        for (int j = 0; j < 32; j++) acc[j] = fmaf(av, wr[j], acc[j]);
    }
#pragma unroll
    for (int j = 0; j < 32; j++)
        wmids[(wbase + j)*64 + lane] = fmaxf(acc[j], 0.f);
    __syncthreads();
    float acc2[32];
#pragma unroll
    for (int j = 0; j < 32; j++) acc2[j] = bof[wbase + j];
#pragma unroll 2
    for (int k = 0; k < 128; k++){
        float wv = wmids[k*64 + lane];
        const float* wr = w21f + k*128 + wbase;
#pragma unroll
        for (int j = 0; j < 32; j++) acc2[j] = fmaf(wv, wr[j], acc2[j]);
    }
#pragma unroll 2
    for (int k = 0; k < 64; k++){
        float gv = gfs[k*65 + lane];
        const float* wr = rwf + k*128 + wbase;
#pragma unroll
        for (int j = 0; j < 32; j++) acc2[j] = fmaf(gv, wr[j], acc2[j]);
    }
#pragma unroll
    for (int j = 0; j < 32; j++){
        float x = acc2[j];
        float y = 0.5f * x * (1.f + erff(x * 0.70710678118654752f));
#pragma unroll
        for (int off = 1; off < 32; off <<= 1)
            y = fmaxf(y, __shfl_xor(y, off));
        if ((lane & 31) == 0) obuf[(lane >> 5)*128 + wbase + j] = y;
    }
    __syncthreads();
    st(out, (size_t)blockIdx.x*256 + t, obuf[t], F);
}

extern "C" void kernel_launch(void* const* d_in, const int* in_sizes, int n_in,
                              void* d_out, int out_size, void* d_ws, size_t ws_size,
                              hipStream_t stream){
    const void* xyz = d_in[0];
    const void* f   = d_in[1];
    const void* fpt = d_in[2];
    const void* w10 = d_in[3];
    const void* b10 = d_in[4];
    const void* g1  = d_in[5];
    const void* bt1 = d_in[6];
    const void* w11 = d_in[7];
    const void* b11 = d_in[8];
    const void* w20 = d_in[9];
    const void* b20 = d_in[10];
    const void* g2  = d_in[11];
    const void* bt2 = d_in[12];
    const void* w21 = d_in[13];
    const void* b21 = d_in[14];
    const void* rw  = d_in[15];
    const void* rb  = d_in[16];

    char* ws = (char*)d_ws;
    float*  nxf  = (float*) (ws + 0);
    int*    idx  = (int*)   (ws + 65536);
    double* M    = (double*)(ws + 655360);
    float*  bn1  = (float*) (ws + 786432);
    double* sums = (double*)(ws + 917504);
    float*  bn2  = (float*) (ws + 1048576);
    int*    flag = (int*)   (ws + 1050624);
    float*  w20f = (float*) (ws + 1114112);
    float*  w21f = (float*) (ws + 1179648);
    float*  rwf  = (float*) (ws + 1245184);
    float*  b20f = (float*) (ws + 1277952);
    float*  bof  = (float*) (ws + 1278464);
    float*  agg  = (float*) (ws + 2097152);

    init_kernel<<<1, 256, 0, stream>>>(xyz, M, sums, flag);
    fps_kernel<<<4, 256, 0, stream>>>(xyz, nxf, d_out, flag);
    ball_kernel<<<dim3(4,4), 256, 0, stream>>>(xyz, nxf, idx, flag);
    bn1_stats<<<1024, 128, 0, stream>>>(xyz, idx, fpt, M, flag);
    bn1_final<<<1, 128, 0, stream>>>(M, w10, b10, g1, bt1, bn1, flag);
    m1_kernel<<<1024, 256, 0, stream>>>(xyz, f, fpt, w10, b10, w11, b11, nxf, idx, bn1, agg, flag);
    bn2_stats<<<256, 256, 0, stream>>>(agg, w20, b20, sums, flag);
    bn2_final<<<1, 128, 0, stream>>>(sums, g2, bt2, bn2, flag);
    prep_kernel<<<132, 256, 0, stream>>>(w20, b20, w21, b21, rw, rb, bn2,
                                         w20f, w21f, rwf, b20f, bof, flag);
    final_kernel<<<2048, 256, 0, stream>>>(agg, f, idx, w20f, b20f, w21f, rwf, bof, d_out, flag);
}